// Round 4
// baseline (315.192 us; speedup 1.0000x reference)
//
#include <hip/hip_runtime.h>
#include <hip/hip_bf16.h>
#include <hip/hip_cooperative_groups.h>

// KGATPGExp: out[e] = sigmoid( logit(noise[e]) + MLP(concat(emb[col],emb[row],emb[src],emb[dst])) )
// Decomposition (validated R2/R3, absmax 3.9e-3 vs thr 2e-2):
//   c[64]   = b1 + emb[src]@W1[256:384] + emb[dst]@W1[384:512]          (edge-invariant)
//   F[n][:] = emb[n]@W1[0:128] + c       (bf16, per node)   } phase 1 (MFMA, HBM-bound)
//   G[n][:] = emb[n]@W1[128:256]         (bf16, per node)   }
//   out[e]  = sigmoid(logit(noise) + b2 + W2 . relu(F[col[e]] + G[row[e]]))   (phase 2)
// R4: single cooperative kernel, grid.sync() between phases (removes last launch gap).
//     __threadfence() both sides of the barrier: ws poison warms other XCDs' L2 with
//     stale 0xAA lines, so F/G writes need device-scope release + acquire.

namespace cg = cooperative_groups;

typedef __bf16 bf16x8 __attribute__((ext_vector_type(8)));
typedef float  f32x16 __attribute__((ext_vector_type(16)));
typedef unsigned short u16;

#define WSTR 264   // sW row stride (u16): 256 + 8 pad
#define Z16 {0.f,0.f,0.f,0.f,0.f,0.f,0.f,0.f,0.f,0.f,0.f,0.f,0.f,0.f,0.f,0.f}

__device__ __forceinline__ unsigned bfbits(float f){       // fp32 -> bf16 bits, RNE
  unsigned u = __builtin_bit_cast(unsigned, f);
  return (u + 0x7fffu + ((u >> 16) & 1u)) >> 16;
}
__device__ __forceinline__ unsigned pk2(float a, float b){ // pack 2 fp32 -> bf16x2 bits
  return bfbits(a) | (bfbits(b) << 16);
}
__device__ __forceinline__ float bflo(unsigned u){ return __builtin_bit_cast(float, u << 16); }
__device__ __forceinline__ float bfhi(unsigned u){ return __builtin_bit_cast(float, u & 0xffff0000u); }

__device__ __forceinline__ float edge_dot(uint4 fv, uint4 gv, float4 w2a, float4 w2b){
  float p = 0.f, h;
  h = fmaxf(bflo(fv.x) + bflo(gv.x), 0.f); p += h * w2a.x;
  h = fmaxf(bfhi(fv.x) + bfhi(gv.x), 0.f); p += h * w2a.y;
  h = fmaxf(bflo(fv.y) + bflo(gv.y), 0.f); p += h * w2a.z;
  h = fmaxf(bfhi(fv.y) + bfhi(gv.y), 0.f); p += h * w2a.w;
  h = fmaxf(bflo(fv.z) + bflo(gv.z), 0.f); p += h * w2b.x;
  h = fmaxf(bfhi(fv.z) + bfhi(gv.z), 0.f); p += h * w2b.y;
  h = fmaxf(bflo(fv.w) + bflo(gv.w), 0.f); p += h * w2b.z;
  h = fmaxf(bfhi(fv.w) + bfhi(gv.w), 0.f); p += h * w2b.w;
  return p;
}

// ---------------------------------------------------------------------------
__global__ __launch_bounds__(256, 3) void fused_kernel(
    const float* __restrict__ embed, const float* __restrict__ W1,
    const float* __restrict__ b1, const int* __restrict__ srcp,
    const int* __restrict__ dstp, const float* __restrict__ W2,
    const float* __restrict__ b2, const float* __restrict__ noise,
    const int* __restrict__ col, const int* __restrict__ row,
    u16* __restrict__ F, u16* __restrict__ G, float* __restrict__ out,
    int NN, int E, int nBlocks)
{
  __shared__ __align__(16) u16 sW[64 * WSTR];
  __shared__ float sC[64];
  __shared__ float sRed[256];
  int tid = threadIdx.x;
  int lane = tid & 63, wave = tid >> 6;

  // --- prologue A: transpose W1[0:256][0:64] fp32 -> sW[n][k] bf16 (L2-hot) ---
  #pragma unroll
  for (int i = 0; i < 16; ++i){
    int idx = i * 256 + tid;               // 4096 float4 reads, fully coalesced
    int k = idx >> 4, q = idx & 15;
    float4 v = *(const float4*)(W1 + k * 64 + q * 4);
    sW[(4*q+0) * WSTR + k] = (u16)bfbits(v.x);
    sW[(4*q+1) * WSTR + k] = (u16)bfbits(v.y);
    sW[(4*q+2) * WSTR + k] = (u16)bfbits(v.z);
    sW[(4*q+3) * WSTR + k] = (u16)bfbits(v.w);
  }
  // --- prologue B: c partials, 4-way k-split across the block ---
  {
    int h = tid & 63, part = tid >> 6;
    int si = srcp[0], di = dstp[0];
    const float* se  = embed + (size_t)si * 128 + part * 32;
    const float* de  = embed + (size_t)di * 128 + part * 32;
    const float* w1s = W1 + (256 + part * 32) * 64 + h;
    const float* w1d = W1 + (384 + part * 32) * 64 + h;
    float acc = 0.f;
    #pragma unroll 8
    for (int k = 0; k < 32; ++k){
      acc += se[k] * w1s[k * 64];
      acc += de[k] * w1d[k * 64];
    }
    sRed[tid] = acc;
  }
  __syncthreads();
  if (tid < 64) sC[tid] = b1[tid] + sRed[tid] + sRed[64+tid] + sRed[128+tid] + sRed[192+tid];
  __syncthreads();

  // --- phase 1: grid-stride over 128-node tiles, MFMA ---
  //   A (emb rows): lane holds A[m=lane&31][k=(lane>>5)*8+j]
  //   B (sW):       lane holds B[k=(lane>>5)*8+j][n=lane&31]
  //   C/D:          col(n)=lane&31, row(m)=(r&3)+8*(r>>2)+4*(lane>>5)
  int nl = lane & 31, h5 = lane >> 5;
  const u16* sw0 = sW + nl * WSTR;             // hidden rows 0..31
  const u16* sw1 = sW + (32 + nl) * WSTR;      // hidden rows 32..63
  float cv0 = sC[nl], cv1 = sC[32 + nl];
  for (int tile0 = blockIdx.x * 128; tile0 < NN; tile0 += nBlocks * 128){
    int tile = tile0 + wave * 32;
    if (tile < NN){                            // NN % 32 == 0
      const float* erow = embed + (size_t)(tile + nl) * 128;
      f32x16 aF0 = Z16, aF1 = Z16, aG0 = Z16, aG1 = Z16;
      #pragma unroll
      for (int s = 0; s < 8; ++s){             // K = 128, 16 per MFMA
        int ko = s * 16 + h5 * 8;
        float4 x = *(const float4*)(erow + ko);
        float4 y = *(const float4*)(erow + ko + 4);
        uint4 u; u.x = pk2(x.x,x.y); u.y = pk2(x.z,x.w); u.z = pk2(y.x,y.y); u.w = pk2(y.z,y.w);
        bf16x8 a = __builtin_bit_cast(bf16x8, u);
        bf16x8 bF0 = *(const bf16x8*)(sw0 + ko);
        bf16x8 bF1 = *(const bf16x8*)(sw1 + ko);
        bf16x8 bG0 = *(const bf16x8*)(sw0 + 128 + ko);   // W1b at k=128..255
        bf16x8 bG1 = *(const bf16x8*)(sw1 + 128 + ko);
        aF0 = __builtin_amdgcn_mfma_f32_32x32x16_bf16(a, bF0, aF0, 0, 0, 0);
        aF1 = __builtin_amdgcn_mfma_f32_32x32x16_bf16(a, bF1, aF1, 0, 0, 0);
        aG0 = __builtin_amdgcn_mfma_f32_32x32x16_bf16(a, bG0, aG0, 0, 0, 0);
        aG1 = __builtin_amdgcn_mfma_f32_32x32x16_bf16(a, bG1, aG1, 0, 0, 0);
      }
      #pragma unroll
      for (int r = 0; r < 16; ++r){
        int node = tile + (r & 3) + 8 * (r >> 2) + 4 * h5;
        u16* fr = F + (size_t)node * 64 + nl;
        u16* gr = G + (size_t)node * 64 + nl;
        fr[0]  = (u16)bfbits(aF0[r] + cv0);    // fold c into F
        fr[32] = (u16)bfbits(aF1[r] + cv1);
        gr[0]  = (u16)bfbits(aG0[r]);
        gr[32] = (u16)bfbits(aG1[r]);
      }
    }
  }

  // --- device-scope release; grid barrier; acquire ---
  __threadfence();
  cg::this_grid().sync();
  __threadfence();

  // --- phase 2: grid-stride over edges, 2 octets per wave per iter ---
  // 8 lanes per edge, lane j handles hidden [8j,8j+8) as one 16 B gather.
  int j = lane & 7, grp = lane >> 3;
  float4 w2a = ((const float4*)W2)[2 * j];
  float4 w2b = ((const float4*)W2)[2 * j + 1];
  float b2v = b2[0];
  int wgid = blockIdx.x * 4 + wave;
  int stride = nBlocks * 4 * 16;
  for (int base = wgid * 16; base < E; base += stride){
    int eA = base + grp;
    int eB = base + 8 + grp;
    int eAc = eA < E ? eA : E - 1;             // clamp loads; stores masked
    int eBc = eB < E ? eB : E - 1;
    int ciA = col[eAc], riA = row[eAc];
    int ciB = col[eBc], riB = row[eBc];
    uint4 fvA = ((const uint4*)(F + (size_t)ciA * 64))[j];
    uint4 gvA = ((const uint4*)(G + (size_t)riA * 64))[j];
    uint4 fvB = ((const uint4*)(F + (size_t)ciB * 64))[j];
    uint4 gvB = ((const uint4*)(G + (size_t)riB * 64))[j];
    float pA = edge_dot(fvA, gvA, w2a, w2b);
    float pB = edge_dot(fvB, gvB, w2a, w2b);
    pA += __shfl_xor(pA, 1, 64); pB += __shfl_xor(pB, 1, 64);
    pA += __shfl_xor(pA, 2, 64); pB += __shfl_xor(pB, 2, 64);
    pA += __shfl_xor(pA, 4, 64); pB += __shfl_xor(pB, 4, 64);
    if (j == 0){
      if (eA < E){
        float ns = noise[eA];
        float g = logf(ns) - log1pf(-ns) + pA + b2v;
        out[eA] = 1.f / (1.f + expf(-g));
      }
      if (eB < E){
        float ns = noise[eB];
        float g = logf(ns) - log1pf(-ns) + pB + b2v;
        out[eB] = 1.f / (1.f + expf(-g));
      }
    }
  }
}

// ---------------------------------------------------------------------------
// Insurance path if ws_size is too small for F/G tables: correct-but-slow fp32.
__global__ void naive_kernel(const float* __restrict__ embed, const float* __restrict__ W1,
    const float* __restrict__ b1, const float* __restrict__ W2, const float* __restrict__ b2,
    const float* __restrict__ noise, const int* __restrict__ col, const int* __restrict__ row,
    const int* __restrict__ srcp, const int* __restrict__ dstp, float* __restrict__ out, int E)
{
  int e = blockIdx.x * 256 + threadIdx.x;
  if (e >= E) return;
  int ci = col[e], ri = row[e], si = srcp[0], di = dstp[0];
  const float* ce = embed + (size_t)ci * 128;
  const float* re = embed + (size_t)ri * 128;
  const float* se = embed + (size_t)si * 128;
  const float* de = embed + (size_t)di * 128;
  float w = b2[0];
  for (int jj = 0; jj < 64; ++jj){
    float hh = b1[jj];
    for (int k = 0; k < 128; ++k){
      hh += ce[k] * W1[k * 64 + jj] + re[k] * W1[(128 + k) * 64 + jj]
          + se[k] * W1[(256 + k) * 64 + jj] + de[k] * W1[(384 + k) * 64 + jj];
    }
    w += fmaxf(hh, 0.f) * W2[jj];
  }
  float ns = noise[e];
  float g = logf(ns) - log1pf(-ns) + w;
  out[e] = 1.f / (1.f + expf(-g));
}

// ---------------------------------------------------------------------------
extern "C" void kernel_launch(void* const* d_in, const int* in_sizes, int n_in,
                              void* d_out, int out_size, void* d_ws, size_t ws_size,
                              hipStream_t stream)
{
  const float* embed = (const float*)d_in[0];
  const float* W1    = (const float*)d_in[1];
  const float* b1    = (const float*)d_in[2];
  const float* W2    = (const float*)d_in[3];
  const float* b2    = (const float*)d_in[4];
  const float* noise = (const float*)d_in[5];
  const int*   col   = (const int*)d_in[6];
  const int*   rowp  = (const int*)d_in[7];
  const int*   srcp  = (const int*)d_in[8];
  const int*   dstp  = (const int*)d_in[9];
  int E  = in_sizes[5];
  int NN = in_sizes[0] / 128;
  float* out = (float*)d_out;

  const size_t fBytes = (size_t)NN * 64 * sizeof(u16);
  if (ws_size >= 2 * fBytes){
    u16* F = (u16*)d_ws;
    u16* G = (u16*)((char*)d_ws + fBytes);
    // Co-resident grid: occupancy query (host-side, graph-capture-safe).
    int dev = 0; hipGetDevice(&dev);
    int nCU = 256;
    hipDeviceGetAttribute(&nCU, hipDeviceAttributeMultiprocessorCount, dev);
    int occ = 1;
    hipOccupancyMaxActiveBlocksPerMultiprocessor(&occ, fused_kernel, 256, 0);
    if (occ < 1) occ = 1;
    int nBlocks = nCU * occ;
    int maxUseful = (NN + 127) / 128;          // phase-1 tiles bound the useful grid
    if (nBlocks > maxUseful) nBlocks = maxUseful;
    void* args[] = { (void*)&embed, (void*)&W1, (void*)&b1, (void*)&srcp, (void*)&dstp,
                     (void*)&W2, (void*)&b2, (void*)&noise, (void*)&col, (void*)&rowp,
                     (void*)&F, (void*)&G, (void*)&out, (void*)&NN, (void*)&E,
                     (void*)&nBlocks };
    hipLaunchCooperativeKernel((const void*)fused_kernel, dim3(nBlocks), dim3(256),
                               args, 0, stream);
  } else {
    naive_kernel<<<(E + 255) / 256, 256, 0, stream>>>(embed, W1, b1, W2, b2, noise,
                                                      col, rowp, srcp, dstp, out, E);
  }
}

// Round 5
// 178.441 us; speedup vs baseline: 1.7664x; 1.7664x over previous
//
#include <hip/hip_runtime.h>
#include <hip/hip_bf16.h>

// KGATPGExp: out[e] = sigmoid( logit(noise[e]) + MLP(concat(emb[col],emb[row],emb[src],emb[dst])) )
// Decomposition (validated R2/R3, absmax 3.9e-3 vs thr 2e-2):
//   c[64]   = b1 + emb[src]@W1[256:384] + emb[dst]@W1[384:512]          (edge-invariant)
//   F[n][:] = emb[n]@W1[0:128] + c       (bf16, per node)   } fg_kernel (MFMA, HBM-bound)
//   G[n][:] = emb[n]@W1[128:256]         (bf16, per node)   }
//   out[e]  = sigmoid(logit(noise) + b2 + W2 . relu(F[col[e]] + G[row[e]]))   (edge_kernel)
// R4 post-mortem: cooperative fusion + per-thread __threadfence() = L2 wbinv storm
//   (290 us @ 4% HBM). Kernel-boundary coherence is the cheap path — reverted.
// R5: R3 structure + one-thread-per-edge edge_kernel (16 outstanding gathers/thread,
//   W2 via scalar loads, no shuffles).

typedef __bf16 bf16x8 __attribute__((ext_vector_type(8)));
typedef float  f32x16 __attribute__((ext_vector_type(16)));
typedef unsigned short u16;

#define WSTR 264   // sW row stride (u16): 256 + 8 pad
#define Z16 {0.f,0.f,0.f,0.f,0.f,0.f,0.f,0.f,0.f,0.f,0.f,0.f,0.f,0.f,0.f,0.f}

__device__ __forceinline__ unsigned bfbits(float f){       // fp32 -> bf16 bits, RNE
  unsigned u = __builtin_bit_cast(unsigned, f);
  return (u + 0x7fffu + ((u >> 16) & 1u)) >> 16;
}
__device__ __forceinline__ unsigned pk2(float a, float b){ // pack 2 fp32 -> bf16x2 bits
  return bfbits(a) | (bfbits(b) << 16);
}
__device__ __forceinline__ float bflo(unsigned u){ return __builtin_bit_cast(float, u << 16); }
__device__ __forceinline__ float bfhi(unsigned u){ return __builtin_bit_cast(float, u & 0xffff0000u); }

// ---------------------------------------------------------------------------
// fg: F = emb@W1a + c, G = emb@W1b over all nodes. One 32-node tile per wave,
// 4 waves (128 nodes) per block. Per-block prologue builds the bf16 transposed
// W1[0:256] in LDS and the c vector (both from L2-hot W1).
//   A (emb rows, streamed):  lane holds A[m=lane&31][k=(lane>>5)*8+j]
//   B (sW from LDS):         lane holds B[k=(lane>>5)*8+j][n=lane&31]
//   C/D:                     col(n)=lane&31, row(m)=(r&3)+8*(r>>2)+4*(lane>>5)
__global__ __launch_bounds__(256, 4) void fg_kernel(
    const float* __restrict__ embed, const float* __restrict__ W1,
    const float* __restrict__ b1, const int* __restrict__ srcp,
    const int* __restrict__ dstp, u16* __restrict__ F, u16* __restrict__ G, int NN)
{
  __shared__ __align__(16) u16 sW[64 * WSTR];
  __shared__ float sC[64];
  __shared__ float sRed[256];
  int tid = threadIdx.x;

  // --- prologue A: transpose W1[0:256][0:64] fp32 -> sW[n][k] bf16 (L2-hot) ---
  #pragma unroll
  for (int i = 0; i < 16; ++i){
    int idx = i * 256 + tid;               // 4096 float4 reads, fully coalesced
    int k = idx >> 4, q = idx & 15;
    float4 v = *(const float4*)(W1 + k * 64 + q * 4);
    sW[(4*q+0) * WSTR + k] = (u16)bfbits(v.x);
    sW[(4*q+1) * WSTR + k] = (u16)bfbits(v.y);
    sW[(4*q+2) * WSTR + k] = (u16)bfbits(v.z);
    sW[(4*q+3) * WSTR + k] = (u16)bfbits(v.w);
  }
  // --- prologue B: c partials, 4-way k-split across the block ---
  {
    int h = tid & 63, part = tid >> 6;
    int si = srcp[0], di = dstp[0];
    const float* se  = embed + (size_t)si * 128 + part * 32;
    const float* de  = embed + (size_t)di * 128 + part * 32;
    const float* w1s = W1 + (256 + part * 32) * 64 + h;
    const float* w1d = W1 + (384 + part * 32) * 64 + h;
    float acc = 0.f;
    #pragma unroll 8
    for (int k = 0; k < 32; ++k){
      acc += se[k] * w1s[k * 64];
      acc += de[k] * w1d[k * 64];
    }
    sRed[tid] = acc;
  }
  __syncthreads();
  if (tid < 64) sC[tid] = b1[tid] + sRed[tid] + sRed[64+tid] + sRed[128+tid] + sRed[192+tid];
  __syncthreads();

  // --- main MFMA loop ---
  int lane = tid & 63, wave = tid >> 6;
  int nl = lane & 31, h5 = lane >> 5;
  int tile = blockIdx.x * 128 + wave * 32;
  if (tile >= NN) return;                      // NN % 32 == 0; barriers already passed
  const float* erow = embed + (size_t)(tile + nl) * 128;
  f32x16 aF0 = Z16, aF1 = Z16, aG0 = Z16, aG1 = Z16;
  const u16* sw0 = sW + nl * WSTR;             // hidden rows 0..31
  const u16* sw1 = sW + (32 + nl) * WSTR;      // hidden rows 32..63
  #pragma unroll
  for (int s = 0; s < 8; ++s){                 // K = 128, 16 per MFMA
    int ko = s * 16 + h5 * 8;
    float4 x = *(const float4*)(erow + ko);
    float4 y = *(const float4*)(erow + ko + 4);
    uint4 u; u.x = pk2(x.x,x.y); u.y = pk2(x.z,x.w); u.z = pk2(y.x,y.y); u.w = pk2(y.z,y.w);
    bf16x8 a = __builtin_bit_cast(bf16x8, u);
    bf16x8 bF0 = *(const bf16x8*)(sw0 + ko);
    bf16x8 bF1 = *(const bf16x8*)(sw1 + ko);
    bf16x8 bG0 = *(const bf16x8*)(sw0 + 128 + ko);   // W1b at k=128..255
    bf16x8 bG1 = *(const bf16x8*)(sw1 + 128 + ko);
    aF0 = __builtin_amdgcn_mfma_f32_32x32x16_bf16(a, bF0, aF0, 0, 0, 0);
    aF1 = __builtin_amdgcn_mfma_f32_32x32x16_bf16(a, bF1, aF1, 0, 0, 0);
    aG0 = __builtin_amdgcn_mfma_f32_32x32x16_bf16(a, bG0, aG0, 0, 0, 0);
    aG1 = __builtin_amdgcn_mfma_f32_32x32x16_bf16(a, bG1, aG1, 0, 0, 0);
  }
  float cv0 = sC[nl], cv1 = sC[32 + nl];
  #pragma unroll
  for (int r = 0; r < 16; ++r){
    int node = tile + (r & 3) + 8 * (r >> 2) + 4 * h5;
    u16* fr = F + (size_t)node * 64 + nl;
    u16* gr = G + (size_t)node * 64 + nl;
    fr[0]  = (u16)bfbits(aF0[r] + cv0);        // fold c into F
    fr[32] = (u16)bfbits(aF1[r] + cv1);
    gr[0]  = (u16)bfbits(aG0[r]);
    gr[32] = (u16)bfbits(aG1[r]);
  }
}

// ---------------------------------------------------------------------------
// edge: ONE THREAD PER EDGE. 16 independent 16 B gathers per thread (two batches
// of 8 for VGPR pressure), W2 wave-uniform -> scalar loads, no cross-lane reduce.
__device__ __forceinline__ float acc8(uint4 fv, uint4 gv, const float* __restrict__ w2){
  float p = 0.f, h;
  h = fmaxf(bflo(fv.x) + bflo(gv.x), 0.f); p += h * w2[0];
  h = fmaxf(bfhi(fv.x) + bfhi(gv.x), 0.f); p += h * w2[1];
  h = fmaxf(bflo(fv.y) + bflo(gv.y), 0.f); p += h * w2[2];
  h = fmaxf(bfhi(fv.y) + bfhi(gv.y), 0.f); p += h * w2[3];
  h = fmaxf(bflo(fv.z) + bflo(gv.z), 0.f); p += h * w2[4];
  h = fmaxf(bfhi(fv.z) + bfhi(gv.z), 0.f); p += h * w2[5];
  h = fmaxf(bflo(fv.w) + bflo(gv.w), 0.f); p += h * w2[6];
  h = fmaxf(bfhi(fv.w) + bfhi(gv.w), 0.f); p += h * w2[7];
  return p;
}

__global__ __launch_bounds__(256, 8) void edge_kernel(
    const u16* __restrict__ F, const u16* __restrict__ G,
    const float* __restrict__ W2, const float* __restrict__ b2,
    const float* __restrict__ noise, const int* __restrict__ col,
    const int* __restrict__ row, float* __restrict__ out, int E)
{
  int e = blockIdx.x * 256 + threadIdx.x;
  if (e >= E) return;
  int ci = col[e], ri = row[e];
  float ns = noise[e];
  const uint4* fp = (const uint4*)(F + (size_t)ci * 64);
  const uint4* gp = (const uint4*)(G + (size_t)ri * 64);
  // batch 1: hidden 0..31 (8 outstanding gathers)
  uint4 f0 = fp[0], f1 = fp[1], f2 = fp[2], f3 = fp[3];
  uint4 g0 = gp[0], g1 = gp[1], g2 = gp[2], g3 = gp[3];
  float p = acc8(f0, g0, W2) + acc8(f1, g1, W2 + 8)
          + acc8(f2, g2, W2 + 16) + acc8(f3, g3, W2 + 24);
  // batch 2: hidden 32..63
  uint4 f4 = fp[4], f5 = fp[5], f6 = fp[6], f7 = fp[7];
  uint4 g4 = gp[4], g5 = gp[5], g6 = gp[6], g7 = gp[7];
  p += acc8(f4, g4, W2 + 32) + acc8(f5, g5, W2 + 40)
     + acc8(f6, g6, W2 + 48) + acc8(f7, g7, W2 + 56);
  float g = logf(ns) - log1pf(-ns) + p + b2[0];
  out[e] = 1.f / (1.f + expf(-g));
}

// ---------------------------------------------------------------------------
// Insurance path if ws_size is too small for F/G tables: correct-but-slow fp32.
__global__ void naive_kernel(const float* __restrict__ embed, const float* __restrict__ W1,
    const float* __restrict__ b1, const float* __restrict__ W2, const float* __restrict__ b2,
    const float* __restrict__ noise, const int* __restrict__ col, const int* __restrict__ row,
    const int* __restrict__ srcp, const int* __restrict__ dstp, float* __restrict__ out, int E)
{
  int e = blockIdx.x * 256 + threadIdx.x;
  if (e >= E) return;
  int ci = col[e], ri = row[e], si = srcp[0], di = dstp[0];
  const float* ce = embed + (size_t)ci * 128;
  const float* re = embed + (size_t)ri * 128;
  const float* se = embed + (size_t)si * 128;
  const float* de = embed + (size_t)di * 128;
  float w = b2[0];
  for (int jj = 0; jj < 64; ++jj){
    float hh = b1[jj];
    for (int k = 0; k < 128; ++k){
      hh += ce[k] * W1[k * 64 + jj] + re[k] * W1[(128 + k) * 64 + jj]
          + se[k] * W1[(256 + k) * 64 + jj] + de[k] * W1[(384 + k) * 64 + jj];
    }
    w += fmaxf(hh, 0.f) * W2[jj];
  }
  float ns = noise[e];
  float g = logf(ns) - log1pf(-ns) + w;
  out[e] = 1.f / (1.f + expf(-g));
}

// ---------------------------------------------------------------------------
extern "C" void kernel_launch(void* const* d_in, const int* in_sizes, int n_in,
                              void* d_out, int out_size, void* d_ws, size_t ws_size,
                              hipStream_t stream)
{
  const float* embed = (const float*)d_in[0];
  const float* W1    = (const float*)d_in[1];
  const float* b1    = (const float*)d_in[2];
  const float* W2    = (const float*)d_in[3];
  const float* b2    = (const float*)d_in[4];
  const float* noise = (const float*)d_in[5];
  const int*   col   = (const int*)d_in[6];
  const int*   rowp  = (const int*)d_in[7];
  const int*   srcp  = (const int*)d_in[8];
  const int*   dstp  = (const int*)d_in[9];
  const int E  = in_sizes[5];
  const int NN = in_sizes[0] / 128;
  float* out = (float*)d_out;

  const size_t fBytes = (size_t)NN * 64 * sizeof(u16);
  if (ws_size >= 2 * fBytes){
    u16* F = (u16*)d_ws;
    u16* G = (u16*)((char*)d_ws + fBytes);
    fg_kernel<<<(NN + 127) / 128, 256, 0, stream>>>(embed, W1, b1, srcp, dstp, F, G, NN);
    edge_kernel<<<(E + 255) / 256, 256, 0, stream>>>(F, G, W2, b2, noise, col, rowp, out, E);
  } else {
    naive_kernel<<<(E + 255) / 256, 256, 0, stream>>>(embed, W1, b1, W2, b2, noise,
                                                      col, rowp, srcp, dstp, out, E);
  }
}

// Round 6
// 145.968 us; speedup vs baseline: 2.1593x; 1.2225x over previous
//
#include <hip/hip_runtime.h>
#include <hip/hip_bf16.h>

// KGATPGExp: out[e] = sigmoid( logit(noise[e]) + MLP(concat(emb[col],emb[row],emb[src],emb[dst])) )
// Decomposition (validated R2+, absmax 3.9e-3 vs thr 2e-2):
//   c[64]   = b1 + emb[src]@W1[256:384] + emb[dst]@W1[384:512]          (edge-invariant)
//   F[n][:] = emb[n]@W1[0:128] + c       (bf16, per node)   } fg_kernel (MFMA, HBM-bound)
//   G[n][:] = emb[n]@W1[128:256]         (bf16, per node)   }
//   out[e]  = sigmoid(logit(noise) + b2 + W2 . relu(F[col[e]] + G[row[e]]))   (edge_kernel)
// R4 post-mortem: cooperative fusion + per-thread fences = L2 wbinv storm. Reverted.
// R5 post-mortem: one-thread-per-edge gathers = 64 distinct lines per instruction
//   (8x transaction rate) -> 62 us. Coalescing beats per-thread ILP here.
// R6: 8-lanes-per-edge (8 merged line-requests/instr) + 4 octets in flight per wave
//   (32 edges/wave, all 8 gathers issued before any use).

typedef __bf16 bf16x8 __attribute__((ext_vector_type(8)));
typedef float  f32x16 __attribute__((ext_vector_type(16)));
typedef unsigned short u16;

#define WSTR 264   // sW row stride (u16): 256 + 8 pad
#define Z16 {0.f,0.f,0.f,0.f,0.f,0.f,0.f,0.f,0.f,0.f,0.f,0.f,0.f,0.f,0.f,0.f}

__device__ __forceinline__ unsigned bfbits(float f){       // fp32 -> bf16 bits, RNE
  unsigned u = __builtin_bit_cast(unsigned, f);
  return (u + 0x7fffu + ((u >> 16) & 1u)) >> 16;
}
__device__ __forceinline__ unsigned pk2(float a, float b){ // pack 2 fp32 -> bf16x2 bits
  return bfbits(a) | (bfbits(b) << 16);
}
__device__ __forceinline__ float bflo(unsigned u){ return __builtin_bit_cast(float, u << 16); }
__device__ __forceinline__ float bfhi(unsigned u){ return __builtin_bit_cast(float, u & 0xffff0000u); }

__device__ __forceinline__ float edge_dot(uint4 fv, uint4 gv, float4 w2a, float4 w2b){
  float p = 0.f, h;
  h = fmaxf(bflo(fv.x) + bflo(gv.x), 0.f); p += h * w2a.x;
  h = fmaxf(bfhi(fv.x) + bfhi(gv.x), 0.f); p += h * w2a.y;
  h = fmaxf(bflo(fv.y) + bflo(gv.y), 0.f); p += h * w2a.z;
  h = fmaxf(bfhi(fv.y) + bfhi(gv.y), 0.f); p += h * w2a.w;
  h = fmaxf(bflo(fv.z) + bflo(gv.z), 0.f); p += h * w2b.x;
  h = fmaxf(bfhi(fv.z) + bfhi(gv.z), 0.f); p += h * w2b.y;
  h = fmaxf(bflo(fv.w) + bflo(gv.w), 0.f); p += h * w2b.z;
  h = fmaxf(bfhi(fv.w) + bfhi(gv.w), 0.f); p += h * w2b.w;
  return p;
}

// ---------------------------------------------------------------------------
// fg: F = emb@W1a + c, G = emb@W1b over all nodes. One 32-node tile per wave,
// 4 waves (128 nodes) per block. Per-block prologue builds the bf16 transposed
// W1[0:256] in LDS and the c vector (both from L2-hot W1).
//   A (emb rows, streamed):  lane holds A[m=lane&31][k=(lane>>5)*8+j]
//   B (sW from LDS):         lane holds B[k=(lane>>5)*8+j][n=lane&31]
//   C/D:                     col(n)=lane&31, row(m)=(r&3)+8*(r>>2)+4*(lane>>5)
__global__ __launch_bounds__(256, 4) void fg_kernel(
    const float* __restrict__ embed, const float* __restrict__ W1,
    const float* __restrict__ b1, const int* __restrict__ srcp,
    const int* __restrict__ dstp, u16* __restrict__ F, u16* __restrict__ G, int NN)
{
  __shared__ __align__(16) u16 sW[64 * WSTR];
  __shared__ float sC[64];
  __shared__ float sRed[256];
  int tid = threadIdx.x;

  // --- prologue A: transpose W1[0:256][0:64] fp32 -> sW[n][k] bf16 (L2-hot) ---
  #pragma unroll
  for (int i = 0; i < 16; ++i){
    int idx = i * 256 + tid;               // 4096 float4 reads, fully coalesced
    int k = idx >> 4, q = idx & 15;
    float4 v = *(const float4*)(W1 + k * 64 + q * 4);
    sW[(4*q+0) * WSTR + k] = (u16)bfbits(v.x);
    sW[(4*q+1) * WSTR + k] = (u16)bfbits(v.y);
    sW[(4*q+2) * WSTR + k] = (u16)bfbits(v.z);
    sW[(4*q+3) * WSTR + k] = (u16)bfbits(v.w);
  }
  // --- prologue B: c partials, 4-way k-split across the block ---
  {
    int h = tid & 63, part = tid >> 6;
    int si = srcp[0], di = dstp[0];
    const float* se  = embed + (size_t)si * 128 + part * 32;
    const float* de  = embed + (size_t)di * 128 + part * 32;
    const float* w1s = W1 + (256 + part * 32) * 64 + h;
    const float* w1d = W1 + (384 + part * 32) * 64 + h;
    float acc = 0.f;
    #pragma unroll 8
    for (int k = 0; k < 32; ++k){
      acc += se[k] * w1s[k * 64];
      acc += de[k] * w1d[k * 64];
    }
    sRed[tid] = acc;
  }
  __syncthreads();
  if (tid < 64) sC[tid] = b1[tid] + sRed[tid] + sRed[64+tid] + sRed[128+tid] + sRed[192+tid];
  __syncthreads();

  // --- main MFMA loop ---
  int lane = tid & 63, wave = tid >> 6;
  int nl = lane & 31, h5 = lane >> 5;
  int tile = blockIdx.x * 128 + wave * 32;
  if (tile >= NN) return;                      // NN % 32 == 0; barriers already passed
  const float* erow = embed + (size_t)(tile + nl) * 128;
  f32x16 aF0 = Z16, aF1 = Z16, aG0 = Z16, aG1 = Z16;
  const u16* sw0 = sW + nl * WSTR;             // hidden rows 0..31
  const u16* sw1 = sW + (32 + nl) * WSTR;      // hidden rows 32..63
  #pragma unroll
  for (int s = 0; s < 8; ++s){                 // K = 128, 16 per MFMA
    int ko = s * 16 + h5 * 8;
    float4 x = *(const float4*)(erow + ko);
    float4 y = *(const float4*)(erow + ko + 4);
    uint4 u; u.x = pk2(x.x,x.y); u.y = pk2(x.z,x.w); u.z = pk2(y.x,y.y); u.w = pk2(y.z,y.w);
    bf16x8 a = __builtin_bit_cast(bf16x8, u);
    bf16x8 bF0 = *(const bf16x8*)(sw0 + ko);
    bf16x8 bF1 = *(const bf16x8*)(sw1 + ko);
    bf16x8 bG0 = *(const bf16x8*)(sw0 + 128 + ko);   // W1b at k=128..255
    bf16x8 bG1 = *(const bf16x8*)(sw1 + 128 + ko);
    aF0 = __builtin_amdgcn_mfma_f32_32x32x16_bf16(a, bF0, aF0, 0, 0, 0);
    aF1 = __builtin_amdgcn_mfma_f32_32x32x16_bf16(a, bF1, aF1, 0, 0, 0);
    aG0 = __builtin_amdgcn_mfma_f32_32x32x16_bf16(a, bG0, aG0, 0, 0, 0);
    aG1 = __builtin_amdgcn_mfma_f32_32x32x16_bf16(a, bG1, aG1, 0, 0, 0);
  }
  float cv0 = sC[nl], cv1 = sC[32 + nl];
  #pragma unroll
  for (int r = 0; r < 16; ++r){
    int node = tile + (r & 3) + 8 * (r >> 2) + 4 * h5;
    u16* fr = F + (size_t)node * 64 + nl;
    u16* gr = G + (size_t)node * 64 + nl;
    fr[0]  = (u16)bfbits(aF0[r] + cv0);        // fold c into F
    fr[32] = (u16)bfbits(aF1[r] + cv1);
    gr[0]  = (u16)bfbits(aG0[r]);
    gr[32] = (u16)bfbits(aG1[r]);
  }
}

// ---------------------------------------------------------------------------
// edge: 8 lanes per edge (lane j reads 16 B chunk j of the 128 B F/G row ->
// 8 merged line-requests per gather instruction). 4 octets (32 edges) per wave,
// all 8 gathers issued before any use.
__global__ __launch_bounds__(256, 8) void edge_kernel(
    const u16* __restrict__ F, const u16* __restrict__ G,
    const float* __restrict__ W2, const float* __restrict__ b2,
    const float* __restrict__ noise, const int* __restrict__ col,
    const int* __restrict__ row, float* __restrict__ out, int E)
{
  int tid = threadIdx.x;
  int lane = tid & 63, wave = tid >> 6;
  int j = lane & 7, grp = lane >> 3;
  int base = blockIdx.x * 128 + wave * 32;     // 32 edges per wave; E % 128 == 0
  if (base >= E) return;
  float4 w2a = ((const float4*)W2)[2 * j];
  float4 w2b = ((const float4*)W2)[2 * j + 1];
  int eA = base + grp, eB = base + 8 + grp, eC = base + 16 + grp, eD = base + 24 + grp;
  int ciA = col[eA], riA = row[eA];
  int ciB = col[eB], riB = row[eB];
  int ciC = col[eC], riC = row[eC];
  int ciD = col[eD], riD = row[eD];
  uint4 fvA = ((const uint4*)(F + (size_t)ciA * 64))[j];
  uint4 gvA = ((const uint4*)(G + (size_t)riA * 64))[j];
  uint4 fvB = ((const uint4*)(F + (size_t)ciB * 64))[j];
  uint4 gvB = ((const uint4*)(G + (size_t)riB * 64))[j];
  uint4 fvC = ((const uint4*)(F + (size_t)ciC * 64))[j];
  uint4 gvC = ((const uint4*)(G + (size_t)riC * 64))[j];
  uint4 fvD = ((const uint4*)(F + (size_t)ciD * 64))[j];
  uint4 gvD = ((const uint4*)(G + (size_t)riD * 64))[j];
  float pA = edge_dot(fvA, gvA, w2a, w2b);
  float pB = edge_dot(fvB, gvB, w2a, w2b);
  float pC = edge_dot(fvC, gvC, w2a, w2b);
  float pD = edge_dot(fvD, gvD, w2a, w2b);
  pA += __shfl_xor(pA, 1, 64); pB += __shfl_xor(pB, 1, 64);
  pC += __shfl_xor(pC, 1, 64); pD += __shfl_xor(pD, 1, 64);
  pA += __shfl_xor(pA, 2, 64); pB += __shfl_xor(pB, 2, 64);
  pC += __shfl_xor(pC, 2, 64); pD += __shfl_xor(pD, 2, 64);
  pA += __shfl_xor(pA, 4, 64); pB += __shfl_xor(pB, 4, 64);
  pC += __shfl_xor(pC, 4, 64); pD += __shfl_xor(pD, 4, 64);
  if (j == 0){
    float b2v = b2[0];
    float nA = noise[eA], nB = noise[eB], nC = noise[eC], nD = noise[eD];
    out[eA] = 1.f / (1.f + expf(-(logf(nA) - log1pf(-nA) + pA + b2v)));
    out[eB] = 1.f / (1.f + expf(-(logf(nB) - log1pf(-nB) + pB + b2v)));
    out[eC] = 1.f / (1.f + expf(-(logf(nC) - log1pf(-nC) + pC + b2v)));
    out[eD] = 1.f / (1.f + expf(-(logf(nD) - log1pf(-nD) + pD + b2v)));
  }
}

// ---------------------------------------------------------------------------
// Insurance path if ws_size is too small for F/G tables: correct-but-slow fp32.
__global__ void naive_kernel(const float* __restrict__ embed, const float* __restrict__ W1,
    const float* __restrict__ b1, const float* __restrict__ W2, const float* __restrict__ b2,
    const float* __restrict__ noise, const int* __restrict__ col, const int* __restrict__ row,
    const int* __restrict__ srcp, const int* __restrict__ dstp, float* __restrict__ out, int E)
{
  int e = blockIdx.x * 256 + threadIdx.x;
  if (e >= E) return;
  int ci = col[e], ri = row[e], si = srcp[0], di = dstp[0];
  const float* ce = embed + (size_t)ci * 128;
  const float* re = embed + (size_t)ri * 128;
  const float* se = embed + (size_t)si * 128;
  const float* de = embed + (size_t)di * 128;
  float w = b2[0];
  for (int jj = 0; jj < 64; ++jj){
    float hh = b1[jj];
    for (int k = 0; k < 128; ++k){
      hh += ce[k] * W1[k * 64 + jj] + re[k] * W1[(128 + k) * 64 + jj]
          + se[k] * W1[(256 + k) * 64 + jj] + de[k] * W1[(384 + k) * 64 + jj];
    }
    w += fmaxf(hh, 0.f) * W2[jj];
  }
  float ns = noise[e];
  float g = logf(ns) - log1pf(-ns) + w;
  out[e] = 1.f / (1.f + expf(-g));
}

// ---------------------------------------------------------------------------
extern "C" void kernel_launch(void* const* d_in, const int* in_sizes, int n_in,
                              void* d_out, int out_size, void* d_ws, size_t ws_size,
                              hipStream_t stream)
{
  const float* embed = (const float*)d_in[0];
  const float* W1    = (const float*)d_in[1];
  const float* b1    = (const float*)d_in[2];
  const float* W2    = (const float*)d_in[3];
  const float* b2    = (const float*)d_in[4];
  const float* noise = (const float*)d_in[5];
  const int*   col   = (const int*)d_in[6];
  const int*   rowp  = (const int*)d_in[7];
  const int*   srcp  = (const int*)d_in[8];
  const int*   dstp  = (const int*)d_in[9];
  const int E  = in_sizes[5];
  const int NN = in_sizes[0] / 128;
  float* out = (float*)d_out;

  const size_t fBytes = (size_t)NN * 64 * sizeof(u16);
  if (ws_size >= 2 * fBytes && (E & 127) == 0){
    u16* F = (u16*)d_ws;
    u16* G = (u16*)((char*)d_ws + fBytes);
    fg_kernel<<<(NN + 127) / 128, 256, 0, stream>>>(embed, W1, b1, srcp, dstp, F, G, NN);
    edge_kernel<<<E / 128, 256, 0, stream>>>(F, G, W2, b2, noise, col, rowp, out, E);
  } else {
    naive_kernel<<<(E + 255) / 256, 256, 0, stream>>>(embed, W1, b1, W2, b2, noise,
                                                      col, rowp, srcp, dstp, out, E);
  }
}

// Round 7
// 142.880 us; speedup vs baseline: 2.2060x; 1.0216x over previous
//
#include <hip/hip_runtime.h>
#include <hip/hip_bf16.h>

// KGATPGExp: out[e] = sigmoid( logit(noise[e]) + MLP(concat(emb[col],emb[row],emb[src],emb[dst])) )
// Decomposition (validated R2+, absmax 3.9e-3 vs thr 2e-2):
//   c[64]   = b1 + emb[src]@W1[256:384] + emb[dst]@W1[384:512]          (edge-invariant)
//   F[n][:] = emb[n]@W1[0:128] + c       (bf16, per node)   } fg_kernel (MFMA, HBM-bound)
//   G[n][:] = emb[n]@W1[128:256]         (bf16, per node)   }
//   out[e]  = sigmoid(logit(noise) + b2 + W2 . relu(F[col[e]] + G[row[e]]))   (edge_kernel)
// R4: cooperative fusion + per-thread fences = L2 wbinv storm. Reverted.
// R5: one-thread-per-edge gathers = 64 lines/instr (8x transaction rate). Reverted.
// R6: coalesced 8-lane/edge + 4 octets/wave fixed edge, but fg launch_bounds(256,4)
//     snuck in (128-VGPR cap -> spill suspect, +12 us vs R3).
// R7: fg back to launch_bounds(256,3) — single-variable revert.

typedef __bf16 bf16x8 __attribute__((ext_vector_type(8)));
typedef float  f32x16 __attribute__((ext_vector_type(16)));
typedef unsigned short u16;

#define WSTR 264   // sW row stride (u16): 256 + 8 pad
#define Z16 {0.f,0.f,0.f,0.f,0.f,0.f,0.f,0.f,0.f,0.f,0.f,0.f,0.f,0.f,0.f,0.f}

__device__ __forceinline__ unsigned bfbits(float f){       // fp32 -> bf16 bits, RNE
  unsigned u = __builtin_bit_cast(unsigned, f);
  return (u + 0x7fffu + ((u >> 16) & 1u)) >> 16;
}
__device__ __forceinline__ unsigned pk2(float a, float b){ // pack 2 fp32 -> bf16x2 bits
  return bfbits(a) | (bfbits(b) << 16);
}
__device__ __forceinline__ float bflo(unsigned u){ return __builtin_bit_cast(float, u << 16); }
__device__ __forceinline__ float bfhi(unsigned u){ return __builtin_bit_cast(float, u & 0xffff0000u); }

__device__ __forceinline__ float edge_dot(uint4 fv, uint4 gv, float4 w2a, float4 w2b){
  float p = 0.f, h;
  h = fmaxf(bflo(fv.x) + bflo(gv.x), 0.f); p += h * w2a.x;
  h = fmaxf(bfhi(fv.x) + bfhi(gv.x), 0.f); p += h * w2a.y;
  h = fmaxf(bflo(fv.y) + bflo(gv.y), 0.f); p += h * w2a.z;
  h = fmaxf(bfhi(fv.y) + bfhi(gv.y), 0.f); p += h * w2a.w;
  h = fmaxf(bflo(fv.z) + bflo(gv.z), 0.f); p += h * w2b.x;
  h = fmaxf(bfhi(fv.z) + bfhi(gv.z), 0.f); p += h * w2b.y;
  h = fmaxf(bflo(fv.w) + bflo(gv.w), 0.f); p += h * w2b.z;
  h = fmaxf(bfhi(fv.w) + bfhi(gv.w), 0.f); p += h * w2b.w;
  return p;
}

// ---------------------------------------------------------------------------
// fg: F = emb@W1a + c, G = emb@W1b over all nodes. One 32-node tile per wave,
// 4 waves (128 nodes) per block. Per-block prologue builds the bf16 transposed
// W1[0:256] in LDS and the c vector (both from L2-hot W1).
//   A (emb rows, streamed):  lane holds A[m=lane&31][k=(lane>>5)*8+j]
//   B (sW from LDS):         lane holds B[k=(lane>>5)*8+j][n=lane&31]
//   C/D:                     col(n)=lane&31, row(m)=(r&3)+8*(r>>2)+4*(lane>>5)
// launch_bounds(256,3): 170-VGPR budget — (256,4) caps at 128 and spills (R6 lesson).
__global__ __launch_bounds__(256, 3) void fg_kernel(
    const float* __restrict__ embed, const float* __restrict__ W1,
    const float* __restrict__ b1, const int* __restrict__ srcp,
    const int* __restrict__ dstp, u16* __restrict__ F, u16* __restrict__ G, int NN)
{
  __shared__ __align__(16) u16 sW[64 * WSTR];
  __shared__ float sC[64];
  __shared__ float sRed[256];
  int tid = threadIdx.x;

  // --- prologue A: transpose W1[0:256][0:64] fp32 -> sW[n][k] bf16 (L2-hot) ---
  #pragma unroll
  for (int i = 0; i < 16; ++i){
    int idx = i * 256 + tid;               // 4096 float4 reads, fully coalesced
    int k = idx >> 4, q = idx & 15;
    float4 v = *(const float4*)(W1 + k * 64 + q * 4);
    sW[(4*q+0) * WSTR + k] = (u16)bfbits(v.x);
    sW[(4*q+1) * WSTR + k] = (u16)bfbits(v.y);
    sW[(4*q+2) * WSTR + k] = (u16)bfbits(v.z);
    sW[(4*q+3) * WSTR + k] = (u16)bfbits(v.w);
  }
  // --- prologue B: c partials, 4-way k-split across the block ---
  {
    int h = tid & 63, part = tid >> 6;
    int si = srcp[0], di = dstp[0];
    const float* se  = embed + (size_t)si * 128 + part * 32;
    const float* de  = embed + (size_t)di * 128 + part * 32;
    const float* w1s = W1 + (256 + part * 32) * 64 + h;
    const float* w1d = W1 + (384 + part * 32) * 64 + h;
    float acc = 0.f;
    #pragma unroll 8
    for (int k = 0; k < 32; ++k){
      acc += se[k] * w1s[k * 64];
      acc += de[k] * w1d[k * 64];
    }
    sRed[tid] = acc;
  }
  __syncthreads();
  if (tid < 64) sC[tid] = b1[tid] + sRed[tid] + sRed[64+tid] + sRed[128+tid] + sRed[192+tid];
  __syncthreads();

  // --- main MFMA loop ---
  int lane = tid & 63, wave = tid >> 6;
  int nl = lane & 31, h5 = lane >> 5;
  int tile = blockIdx.x * 128 + wave * 32;
  if (tile >= NN) return;                      // NN % 32 == 0; barriers already passed
  const float* erow = embed + (size_t)(tile + nl) * 128;
  f32x16 aF0 = Z16, aF1 = Z16, aG0 = Z16, aG1 = Z16;
  const u16* sw0 = sW + nl * WSTR;             // hidden rows 0..31
  const u16* sw1 = sW + (32 + nl) * WSTR;      // hidden rows 32..63
  #pragma unroll
  for (int s = 0; s < 8; ++s){                 // K = 128, 16 per MFMA
    int ko = s * 16 + h5 * 8;
    float4 x = *(const float4*)(erow + ko);
    float4 y = *(const float4*)(erow + ko + 4);
    uint4 u; u.x = pk2(x.x,x.y); u.y = pk2(x.z,x.w); u.z = pk2(y.x,y.y); u.w = pk2(y.z,y.w);
    bf16x8 a = __builtin_bit_cast(bf16x8, u);
    bf16x8 bF0 = *(const bf16x8*)(sw0 + ko);
    bf16x8 bF1 = *(const bf16x8*)(sw1 + ko);
    bf16x8 bG0 = *(const bf16x8*)(sw0 + 128 + ko);   // W1b at k=128..255
    bf16x8 bG1 = *(const bf16x8*)(sw1 + 128 + ko);
    aF0 = __builtin_amdgcn_mfma_f32_32x32x16_bf16(a, bF0, aF0, 0, 0, 0);
    aF1 = __builtin_amdgcn_mfma_f32_32x32x16_bf16(a, bF1, aF1, 0, 0, 0);
    aG0 = __builtin_amdgcn_mfma_f32_32x32x16_bf16(a, bG0, aG0, 0, 0, 0);
    aG1 = __builtin_amdgcn_mfma_f32_32x32x16_bf16(a, bG1, aG1, 0, 0, 0);
  }
  float cv0 = sC[nl], cv1 = sC[32 + nl];
  #pragma unroll
  for (int r = 0; r < 16; ++r){
    int node = tile + (r & 3) + 8 * (r >> 2) + 4 * h5;
    u16* fr = F + (size_t)node * 64 + nl;
    u16* gr = G + (size_t)node * 64 + nl;
    fr[0]  = (u16)bfbits(aF0[r] + cv0);        // fold c into F
    fr[32] = (u16)bfbits(aF1[r] + cv1);
    gr[0]  = (u16)bfbits(aG0[r]);
    gr[32] = (u16)bfbits(aG1[r]);
  }
}

// ---------------------------------------------------------------------------
// edge: 8 lanes per edge (lane j reads 16 B chunk j of the 128 B F/G row ->
// 8 merged line-requests per gather instruction). 4 octets (32 edges) per wave,
// all 8 gathers issued before any use.
__global__ __launch_bounds__(256, 8) void edge_kernel(
    const u16* __restrict__ F, const u16* __restrict__ G,
    const float* __restrict__ W2, const float* __restrict__ b2,
    const float* __restrict__ noise, const int* __restrict__ col,
    const int* __restrict__ row, float* __restrict__ out, int E)
{
  int tid = threadIdx.x;
  int lane = tid & 63, wave = tid >> 6;
  int j = lane & 7, grp = lane >> 3;
  int base = blockIdx.x * 128 + wave * 32;     // 32 edges per wave; E % 128 == 0
  if (base >= E) return;
  float4 w2a = ((const float4*)W2)[2 * j];
  float4 w2b = ((const float4*)W2)[2 * j + 1];
  int eA = base + grp, eB = base + 8 + grp, eC = base + 16 + grp, eD = base + 24 + grp;
  int ciA = col[eA], riA = row[eA];
  int ciB = col[eB], riB = row[eB];
  int ciC = col[eC], riC = row[eC];
  int ciD = col[eD], riD = row[eD];
  uint4 fvA = ((const uint4*)(F + (size_t)ciA * 64))[j];
  uint4 gvA = ((const uint4*)(G + (size_t)riA * 64))[j];
  uint4 fvB = ((const uint4*)(F + (size_t)ciB * 64))[j];
  uint4 gvB = ((const uint4*)(G + (size_t)riB * 64))[j];
  uint4 fvC = ((const uint4*)(F + (size_t)ciC * 64))[j];
  uint4 gvC = ((const uint4*)(G + (size_t)riC * 64))[j];
  uint4 fvD = ((const uint4*)(F + (size_t)ciD * 64))[j];
  uint4 gvD = ((const uint4*)(G + (size_t)riD * 64))[j];
  float pA = edge_dot(fvA, gvA, w2a, w2b);
  float pB = edge_dot(fvB, gvB, w2a, w2b);
  float pC = edge_dot(fvC, gvC, w2a, w2b);
  float pD = edge_dot(fvD, gvD, w2a, w2b);
  pA += __shfl_xor(pA, 1, 64); pB += __shfl_xor(pB, 1, 64);
  pC += __shfl_xor(pC, 1, 64); pD += __shfl_xor(pD, 1, 64);
  pA += __shfl_xor(pA, 2, 64); pB += __shfl_xor(pB, 2, 64);
  pC += __shfl_xor(pC, 2, 64); pD += __shfl_xor(pD, 2, 64);
  pA += __shfl_xor(pA, 4, 64); pB += __shfl_xor(pB, 4, 64);
  pC += __shfl_xor(pC, 4, 64); pD += __shfl_xor(pD, 4, 64);
  if (j == 0){
    float b2v = b2[0];
    float nA = noise[eA], nB = noise[eB], nC = noise[eC], nD = noise[eD];
    out[eA] = 1.f / (1.f + expf(-(logf(nA) - log1pf(-nA) + pA + b2v)));
    out[eB] = 1.f / (1.f + expf(-(logf(nB) - log1pf(-nB) + pB + b2v)));
    out[eC] = 1.f / (1.f + expf(-(logf(nC) - log1pf(-nC) + pC + b2v)));
    out[eD] = 1.f / (1.f + expf(-(logf(nD) - log1pf(-nD) + pD + b2v)));
  }
}

// ---------------------------------------------------------------------------
// Insurance path if ws_size is too small for F/G tables: correct-but-slow fp32.
__global__ void naive_kernel(const float* __restrict__ embed, const float* __restrict__ W1,
    const float* __restrict__ b1, const float* __restrict__ W2, const float* __restrict__ b2,
    const float* __restrict__ noise, const int* __restrict__ col, const int* __restrict__ row,
    const int* __restrict__ srcp, const int* __restrict__ dstp, float* __restrict__ out, int E)
{
  int e = blockIdx.x * 256 + threadIdx.x;
  if (e >= E) return;
  int ci = col[e], ri = row[e], si = srcp[0], di = dstp[0];
  const float* ce = embed + (size_t)ci * 128;
  const float* re = embed + (size_t)ri * 128;
  const float* se = embed + (size_t)si * 128;
  const float* de = embed + (size_t)di * 128;
  float w = b2[0];
  for (int jj = 0; jj < 64; ++jj){
    float hh = b1[jj];
    for (int k = 0; k < 128; ++k){
      hh += ce[k] * W1[k * 64 + jj] + re[k] * W1[(128 + k) * 64 + jj]
          + se[k] * W1[(256 + k) * 64 + jj] + de[k] * W1[(384 + k) * 64 + jj];
    }
    w += fmaxf(hh, 0.f) * W2[jj];
  }
  float ns = noise[e];
  float g = logf(ns) - log1pf(-ns) + w;
  out[e] = 1.f / (1.f + expf(-g));
}

// ---------------------------------------------------------------------------
extern "C" void kernel_launch(void* const* d_in, const int* in_sizes, int n_in,
                              void* d_out, int out_size, void* d_ws, size_t ws_size,
                              hipStream_t stream)
{
  const float* embed = (const float*)d_in[0];
  const float* W1    = (const float*)d_in[1];
  const float* b1    = (const float*)d_in[2];
  const float* W2    = (const float*)d_in[3];
  const float* b2    = (const float*)d_in[4];
  const float* noise = (const float*)d_in[5];
  const int*   col   = (const int*)d_in[6];
  const int*   rowp  = (const int*)d_in[7];
  const int*   srcp  = (const int*)d_in[8];
  const int*   dstp  = (const int*)d_in[9];
  const int E  = in_sizes[5];
  const int NN = in_sizes[0] / 128;
  float* out = (float*)d_out;

  const size_t fBytes = (size_t)NN * 64 * sizeof(u16);
  if (ws_size >= 2 * fBytes && (E & 127) == 0){
    u16* F = (u16*)d_ws;
    u16* G = (u16*)((char*)d_ws + fBytes);
    fg_kernel<<<(NN + 127) / 128, 256, 0, stream>>>(embed, W1, b1, srcp, dstp, F, G, NN);
    edge_kernel<<<E / 128, 256, 0, stream>>>(F, G, W2, b2, noise, col, rowp, out, E);
  } else {
    naive_kernel<<<(E + 255) / 256, 256, 0, stream>>>(embed, W1, b1, W2, b2, noise,
                                                      col, rowp, srcp, dstp, out, E);
  }
}

// Round 8
// 131.859 us; speedup vs baseline: 2.3904x; 1.0836x over previous
//
#include <hip/hip_runtime.h>
#include <hip/hip_bf16.h>

// KGATPGExp: out[e] = sigmoid( logit(noise[e]) + MLP(concat(emb[col],emb[row],emb[src],emb[dst])) )
// Decomposition (validated R2+, absmax 3.9e-3 vs thr 2e-2):
//   c[64]   = b1 + emb[src]@W1[256:384] + emb[dst]@W1[384:512]          (edge-invariant)
//   F[n][:] = emb[n]@W1[0:128] + c       (bf16, per node)   } fg_kernel (MFMA, HBM-bound)
//   G[n][:] = emb[n]@W1[128:256]         (bf16, per node)   }
//   out[e]  = sigmoid(logit(noise) + b2 + W2 . relu(F[col[e]] + G[row[e]]))   (edge_kernel)
// R4: cooperative fusion + per-thread fences = L2 wbinv storm (290us @ 4% HBM). Reverted.
// R5: one-thread-per-edge gathers = 64 lines/instr (8x transaction rate, 62us). Reverted.
// R6: fg launch_bounds(256,4) snuck in: 128-VGPR cap -> spills (+3us, fixed R7).
// R7: 4-octet/wave edge is ~9us slower than R3's 1-octet/wave (batched ILP lengthens
//     per-wave waitcnt chains; TLP is what hides gather latency here).
// R8: exact R3 edge restore — 1 octet/wave, 12500 blocks, minimal per-wave work.

typedef __bf16 bf16x8 __attribute__((ext_vector_type(8)));
typedef float  f32x16 __attribute__((ext_vector_type(16)));
typedef unsigned short u16;

#define WSTR 264   // sW row stride (u16): 256 + 8 pad
#define Z16 {0.f,0.f,0.f,0.f,0.f,0.f,0.f,0.f,0.f,0.f,0.f,0.f,0.f,0.f,0.f,0.f}

__device__ __forceinline__ unsigned bfbits(float f){       // fp32 -> bf16 bits, RNE
  unsigned u = __builtin_bit_cast(unsigned, f);
  return (u + 0x7fffu + ((u >> 16) & 1u)) >> 16;
}
__device__ __forceinline__ unsigned pk2(float a, float b){ // pack 2 fp32 -> bf16x2 bits
  return bfbits(a) | (bfbits(b) << 16);
}
__device__ __forceinline__ float bflo(unsigned u){ return __builtin_bit_cast(float, u << 16); }
__device__ __forceinline__ float bfhi(unsigned u){ return __builtin_bit_cast(float, u & 0xffff0000u); }

// ---------------------------------------------------------------------------
// fg: F = emb@W1a + c, G = emb@W1b over all nodes. One 32-node tile per wave,
// 4 waves (128 nodes) per block. Per-block prologue builds the bf16 transposed
// W1[0:256] in LDS and the c vector (both from L2-hot W1).
//   A (emb rows, streamed):  lane holds A[m=lane&31][k=(lane>>5)*8+j]
//   B (sW from LDS):         lane holds B[k=(lane>>5)*8+j][n=lane&31]
//   C/D:                     col(n)=lane&31, row(m)=(r&3)+8*(r>>2)+4*(lane>>5)
// launch_bounds(256,3): 170-VGPR budget — (256,4) caps at 128 and spills (R6 lesson).
__global__ __launch_bounds__(256, 3) void fg_kernel(
    const float* __restrict__ embed, const float* __restrict__ W1,
    const float* __restrict__ b1, const int* __restrict__ srcp,
    const int* __restrict__ dstp, u16* __restrict__ F, u16* __restrict__ G, int NN)
{
  __shared__ __align__(16) u16 sW[64 * WSTR];
  __shared__ float sC[64];
  __shared__ float sRed[256];
  int tid = threadIdx.x;

  // --- prologue A: transpose W1[0:256][0:64] fp32 -> sW[n][k] bf16 (L2-hot) ---
  #pragma unroll
  for (int i = 0; i < 16; ++i){
    int idx = i * 256 + tid;               // 4096 float4 reads, fully coalesced
    int k = idx >> 4, q = idx & 15;
    float4 v = *(const float4*)(W1 + k * 64 + q * 4);
    sW[(4*q+0) * WSTR + k] = (u16)bfbits(v.x);
    sW[(4*q+1) * WSTR + k] = (u16)bfbits(v.y);
    sW[(4*q+2) * WSTR + k] = (u16)bfbits(v.z);
    sW[(4*q+3) * WSTR + k] = (u16)bfbits(v.w);
  }
  // --- prologue B: c partials, 4-way k-split across the block ---
  {
    int h = tid & 63, part = tid >> 6;
    int si = srcp[0], di = dstp[0];
    const float* se  = embed + (size_t)si * 128 + part * 32;
    const float* de  = embed + (size_t)di * 128 + part * 32;
    const float* w1s = W1 + (256 + part * 32) * 64 + h;
    const float* w1d = W1 + (384 + part * 32) * 64 + h;
    float acc = 0.f;
    #pragma unroll 8
    for (int k = 0; k < 32; ++k){
      acc += se[k] * w1s[k * 64];
      acc += de[k] * w1d[k * 64];
    }
    sRed[tid] = acc;
  }
  __syncthreads();
  if (tid < 64) sC[tid] = b1[tid] + sRed[tid] + sRed[64+tid] + sRed[128+tid] + sRed[192+tid];
  __syncthreads();

  // --- main MFMA loop ---
  int lane = tid & 63, wave = tid >> 6;
  int nl = lane & 31, h5 = lane >> 5;
  int tile = blockIdx.x * 128 + wave * 32;
  if (tile >= NN) return;                      // NN % 32 == 0; barriers already passed
  const float* erow = embed + (size_t)(tile + nl) * 128;
  f32x16 aF0 = Z16, aF1 = Z16, aG0 = Z16, aG1 = Z16;
  const u16* sw0 = sW + nl * WSTR;             // hidden rows 0..31
  const u16* sw1 = sW + (32 + nl) * WSTR;      // hidden rows 32..63
  #pragma unroll
  for (int s = 0; s < 8; ++s){                 // K = 128, 16 per MFMA
    int ko = s * 16 + h5 * 8;
    float4 x = *(const float4*)(erow + ko);
    float4 y = *(const float4*)(erow + ko + 4);
    uint4 u; u.x = pk2(x.x,x.y); u.y = pk2(x.z,x.w); u.z = pk2(y.x,y.y); u.w = pk2(y.z,y.w);
    bf16x8 a = __builtin_bit_cast(bf16x8, u);
    bf16x8 bF0 = *(const bf16x8*)(sw0 + ko);
    bf16x8 bF1 = *(const bf16x8*)(sw1 + ko);
    bf16x8 bG0 = *(const bf16x8*)(sw0 + 128 + ko);   // W1b at k=128..255
    bf16x8 bG1 = *(const bf16x8*)(sw1 + 128 + ko);
    aF0 = __builtin_amdgcn_mfma_f32_32x32x16_bf16(a, bF0, aF0, 0, 0, 0);
    aF1 = __builtin_amdgcn_mfma_f32_32x32x16_bf16(a, bF1, aF1, 0, 0, 0);
    aG0 = __builtin_amdgcn_mfma_f32_32x32x16_bf16(a, bG0, aG0, 0, 0, 0);
    aG1 = __builtin_amdgcn_mfma_f32_32x32x16_bf16(a, bG1, aG1, 0, 0, 0);
  }
  float cv0 = sC[nl], cv1 = sC[32 + nl];
  #pragma unroll
  for (int r = 0; r < 16; ++r){
    int node = tile + (r & 3) + 8 * (r >> 2) + 4 * h5;
    u16* fr = F + (size_t)node * 64 + nl;
    u16* gr = G + (size_t)node * 64 + nl;
    fr[0]  = (u16)bfbits(aF0[r] + cv0);        // fold c into F
    fr[32] = (u16)bfbits(aF1[r] + cv1);
    gr[0]  = (u16)bfbits(aG0[r]);
    gr[32] = (u16)bfbits(aG1[r]);
  }
}

// ---------------------------------------------------------------------------
// edge (R3 shape): 8 lanes per edge, lane j reads 16 B chunk j of the 128 B F/G
// row (8 merged line-requests per gather instruction). ONE octet per wave, no
// loop — 50K waves of minimal work; TLP hides the gather latency.
__global__ __launch_bounds__(256, 8) void edge_kernel(
    const u16* __restrict__ F, const u16* __restrict__ G,
    const float* __restrict__ W2, const float* __restrict__ b2,
    const float* __restrict__ noise, const int* __restrict__ col,
    const int* __restrict__ row, float* __restrict__ out, int E)
{
  int tid = threadIdx.x;
  int lane = tid & 63, wave = tid >> 6;
  int j = lane & 7, grp = lane >> 3;
  int e0 = blockIdx.x * 32 + wave * 8;
  if (e0 >= E) return;                         // wave-uniform
  int e = e0 + grp; if (e >= E) e = E - 1;     // clamp (safe read), store masked below
  int ci = col[e], ri = row[e];
  uint4 fv = ((const uint4*)(F + (size_t)ci * 64))[j];
  uint4 gv = ((const uint4*)(G + (size_t)ri * 64))[j];
  float4 w2a = ((const float4*)W2)[2 * j];
  float4 w2b = ((const float4*)W2)[2 * j + 1];
  float p = 0.f, h;
  h = fmaxf(bflo(fv.x) + bflo(gv.x), 0.f); p += h * w2a.x;
  h = fmaxf(bfhi(fv.x) + bfhi(gv.x), 0.f); p += h * w2a.y;
  h = fmaxf(bflo(fv.y) + bflo(gv.y), 0.f); p += h * w2a.z;
  h = fmaxf(bfhi(fv.y) + bfhi(gv.y), 0.f); p += h * w2a.w;
  h = fmaxf(bflo(fv.z) + bflo(gv.z), 0.f); p += h * w2b.x;
  h = fmaxf(bfhi(fv.z) + bfhi(gv.z), 0.f); p += h * w2b.y;
  h = fmaxf(bflo(fv.w) + bflo(gv.w), 0.f); p += h * w2b.z;
  h = fmaxf(bfhi(fv.w) + bfhi(gv.w), 0.f); p += h * w2b.w;
  p += __shfl_xor(p, 1, 64);
  p += __shfl_xor(p, 2, 64);
  p += __shfl_xor(p, 4, 64);
  if (j == 0 && e0 + grp < E){
    float ns = noise[e];
    float g = logf(ns) - log1pf(-ns) + p + b2[0];
    out[e] = 1.f / (1.f + expf(-g));
  }
}

// ---------------------------------------------------------------------------
// Insurance path if ws_size is too small for F/G tables: correct-but-slow fp32.
__global__ void naive_kernel(const float* __restrict__ embed, const float* __restrict__ W1,
    const float* __restrict__ b1, const float* __restrict__ W2, const float* __restrict__ b2,
    const float* __restrict__ noise, const int* __restrict__ col, const int* __restrict__ row,
    const int* __restrict__ srcp, const int* __restrict__ dstp, float* __restrict__ out, int E)
{
  int e = blockIdx.x * 256 + threadIdx.x;
  if (e >= E) return;
  int ci = col[e], ri = row[e], si = srcp[0], di = dstp[0];
  const float* ce = embed + (size_t)ci * 128;
  const float* re = embed + (size_t)ri * 128;
  const float* se = embed + (size_t)si * 128;
  const float* de = embed + (size_t)di * 128;
  float w = b2[0];
  for (int jj = 0; jj < 64; ++jj){
    float hh = b1[jj];
    for (int k = 0; k < 128; ++k){
      hh += ce[k] * W1[k * 64 + jj] + re[k] * W1[(128 + k) * 64 + jj]
          + se[k] * W1[(256 + k) * 64 + jj] + de[k] * W1[(384 + k) * 64 + jj];
    }
    w += fmaxf(hh, 0.f) * W2[jj];
  }
  float ns = noise[e];
  float g = logf(ns) - log1pf(-ns) + w;
  out[e] = 1.f / (1.f + expf(-g));
}

// ---------------------------------------------------------------------------
extern "C" void kernel_launch(void* const* d_in, const int* in_sizes, int n_in,
                              void* d_out, int out_size, void* d_ws, size_t ws_size,
                              hipStream_t stream)
{
  const float* embed = (const float*)d_in[0];
  const float* W1    = (const float*)d_in[1];
  const float* b1    = (const float*)d_in[2];
  const float* W2    = (const float*)d_in[3];
  const float* b2    = (const float*)d_in[4];
  const float* noise = (const float*)d_in[5];
  const int*   col   = (const int*)d_in[6];
  const int*   rowp  = (const int*)d_in[7];
  const int*   srcp  = (const int*)d_in[8];
  const int*   dstp  = (const int*)d_in[9];
  const int E  = in_sizes[5];
  const int NN = in_sizes[0] / 128;
  float* out = (float*)d_out;

  const size_t fBytes = (size_t)NN * 64 * sizeof(u16);
  if (ws_size >= 2 * fBytes){
    u16* F = (u16*)d_ws;
    u16* G = (u16*)((char*)d_ws + fBytes);
    fg_kernel<<<(NN + 127) / 128, 256, 0, stream>>>(embed, W1, b1, srcp, dstp, F, G, NN);
    edge_kernel<<<(E + 31) / 32, 256, 0, stream>>>(F, G, W2, b2, noise, col, rowp, out, E);
  } else {
    naive_kernel<<<(E + 255) / 256, 256, 0, stream>>>(embed, W1, b1, W2, b2, noise,
                                                      col, rowp, srcp, dstp, out, E);
  }
}